// Round 11
// baseline (91.176 us; speedup 1.0000x reference)
//
#include <hip/hip_runtime.h>

#define IH 512
#define IW 512
#define OH 502
#define OW 502
#define KS 11
#define HO 16                 /* output rows per strip */
#define NPAIR 16              /* strip pairs per channel (strips s and s+16) */
#define NCH 48                /* 16*3 */
#define NBLK (NCH * NPAIR)    /* 768 = exactly 3 blocks/CU */
#define NT 256                /* 256 threads * 2 cols = 512 cols */
#define LROW 528              /* padded LDS row (max read idx 523) */
#define C1f 0.0001f
#define C2f 0.0009f

// Gaussian(sigma=1.5, k=11) weights, precomputed in double precision.
__device__ __constant__ float g_w[KS] = {
    0.00102838f, 0.00759876f, 0.03600077f, 0.10936069f, 0.21300554f,
    0.26601173f, 0.21300554f, 0.10936069f, 0.03600077f, 0.00759876f,
    0.00102838f};

// Raw barrier: drain LDS ops (cross-wave visibility AND our reads complete)
// but leave global prefetch loads in flight (no vmcnt drain).
#define BARRIER() do {                                        \
    asm volatile("s_waitcnt lgkmcnt(0)" ::: "memory");        \
    __builtin_amdgcn_s_barrier();                             \
} while (0)

// vblur rows (2k, 2k+1) of strip SI: row0 taps RX[0..10]; row1 taps
// RX[1..10] + prefetch NX0 as tap 10. All ring indices static.
#define VBLUR(RX, RY, NX0, NY0, SI)                                           \
    {                                                                         \
        float s0[2]={0,0}, s1[2]={0,0}, s2[2]={0,0}, s3[2]={0,0}, s4[2]={0,0};\
        _Pragma("unroll")                                                     \
        for (int tp = 0; tp < KS; ++tp) {                                     \
            const float w = g_w[tp];                                          \
            const float2 xv = RX[tp], yv = RY[tp];                            \
            const float wx0 = w*xv.x, wx1 = w*xv.y;                           \
            const float wy0 = w*yv.x, wy1 = w*yv.y;                           \
            s0[0]+=wx0; s0[1]+=wx1; s1[0]+=wy0; s1[1]+=wy1;                   \
            s2[0]=fmaf(wx0,xv.x,s2[0]); s2[1]=fmaf(wx1,xv.y,s2[1]);           \
            s3[0]=fmaf(wy0,yv.x,s3[0]); s3[1]=fmaf(wy1,yv.y,s3[1]);           \
            s4[0]=fmaf(wx0,yv.x,s4[0]); s4[1]=fmaf(wx1,yv.y,s4[1]);           \
        }                                                                     \
        *(float2*)&lds[SI][0][0][2*t] = make_float2(s0[0], s0[1]);            \
        *(float2*)&lds[SI][1][0][2*t] = make_float2(s1[0], s1[1]);            \
        *(float2*)&lds[SI][2][0][2*t] = make_float2(s2[0], s2[1]);            \
        *(float2*)&lds[SI][3][0][2*t] = make_float2(s3[0], s3[1]);            \
        *(float2*)&lds[SI][4][0][2*t] = make_float2(s4[0], s4[1]);            \
        float u0[2]={0,0}, u1[2]={0,0}, u2[2]={0,0}, u3[2]={0,0}, u4[2]={0,0};\
        _Pragma("unroll")                                                     \
        for (int tp = 0; tp < KS; ++tp) {                                     \
            const float w = g_w[tp];                                          \
            const float2 xv = (tp < KS-1) ? RX[tp+1] : NX0;                   \
            const float2 yv = (tp < KS-1) ? RY[tp+1] : NY0;                   \
            const float wx0 = w*xv.x, wx1 = w*xv.y;                           \
            const float wy0 = w*yv.x, wy1 = w*yv.y;                           \
            u0[0]+=wx0; u0[1]+=wx1; u1[0]+=wy0; u1[1]+=wy1;                   \
            u2[0]=fmaf(wx0,xv.x,u2[0]); u2[1]=fmaf(wx1,xv.y,u2[1]);           \
            u3[0]=fmaf(wy0,yv.x,u3[0]); u3[1]=fmaf(wy1,yv.y,u3[1]);           \
            u4[0]=fmaf(wx0,yv.x,u4[0]); u4[1]=fmaf(wx1,yv.y,u4[1]);           \
        }                                                                     \
        *(float2*)&lds[SI][0][1][2*t] = make_float2(u0[0], u0[1]);            \
        *(float2*)&lds[SI][1][1][2*t] = make_float2(u1[0], u1[1]);            \
        *(float2*)&lds[SI][2][1][2*t] = make_float2(u2[0], u2[1]);            \
        *(float2*)&lds[SI][3][1][2*t] = make_float2(u3[0], u3[1]);            \
        *(float2*)&lds[SI][4][1][2*t] = make_float2(u4[0], u4[1]);            \
    }

// shift ring by 2 (static indices), commit prefetch, issue next 2-row prefetch
#define SHIFTPREF(RX, RY, NX0, NY0, NX1, NY1, R0, KK)                         \
    {                                                                         \
        _Pragma("unroll")                                                     \
        for (int i = 0; i < KS-2; ++i) { RX[i]=RX[i+2]; RY[i]=RY[i+2]; }      \
        RX[KS-2]=NX0; RY[KS-2]=NY0; RX[KS-1]=NX1; RY[KS-1]=NY1;               \
        const int g0 = min((R0)+2*(KK)+13, IH-1);                             \
        const int g1 = min((R0)+2*(KK)+14, IH-1);                             \
        NX0 = *(const float2*)(xc + g0*IW); NY0 = *(const float2*)(yc + g0*IW);\
        NX1 = *(const float2*)(xc + g1*IW); NY1 = *(const float2*)(yc + g1*IW);\
    }

// hblur + ssim for strip SI, rows 2KK (rr=t>>7 selects) into lsum
#define HBLUR(SI, R0, KK)                                                     \
    {                                                                         \
        const int rr = t >> 7;                                                \
        const int c4 = (t & 127) * 4;                                         \
        const int orow = (R0) + 2*(KK) + rr;                                  \
        float m[5][4];                                                        \
        _Pragma("unroll")                                                     \
        for (int q = 0; q < 5; ++q) {                                         \
            float f[16];                                                      \
            _Pragma("unroll")                                                 \
            for (int a = 0; a < 4; ++a)                                       \
                *(float4*)&f[4*a] = *(const float4*)&lds[SI][q][rr][c4+4*a];  \
            _Pragma("unroll")                                                 \
            for (int cc = 0; cc < 4; ++cc) {                                  \
                float s = 0.f;                                                \
                _Pragma("unroll")                                             \
                for (int tp = 0; tp < KS; ++tp)                               \
                    s = fmaf(g_w[tp], f[cc+tp], s);                           \
                m[q][cc] = s;                                                 \
            }                                                                 \
        }                                                                     \
        if (orow < OH) {                                                      \
            _Pragma("unroll")                                                 \
            for (int cc = 0; cc < 4; ++cc) {                                  \
                const int gc = c4 + cc;                                       \
                if (gc < OW) {                                                \
                    const float mux2 = m[0][cc]*m[0][cc];                     \
                    const float muy2 = m[1][cc]*m[1][cc];                     \
                    const float muxy = m[0][cc]*m[1][cc];                     \
                    const float vx = m[2][cc] - mux2;                         \
                    const float vy = m[3][cc] - muy2;                         \
                    const float cxy = m[4][cc] - muxy;                        \
                    const float num = (2.f*muxy + C1f) * (2.f*cxy + C2f);     \
                    const float den = (mux2 + muy2 + C1f) * (vx + vy + C2f);  \
                    float r_ = __builtin_amdgcn_rcpf(den);                    \
                    r_ = r_ * fmaf(-den, r_, 2.0f);   /* Newton step */       \
                    lsum = fmaf(num, r_, lsum);                               \
                }                                                             \
            }                                                                 \
        }                                                                     \
    }

__global__ __launch_bounds__(NT, 1) void ssim_main(const float* __restrict__ x,
                                                   const float* __restrict__ y,
                                                   double* __restrict__ acc,
                                                   unsigned int* __restrict__ cnt,
                                                   float* __restrict__ out) {
    __shared__ float lds[2][5][2][LROW];   /* 2 strips x 5 q x 2 rows: 42 KB */
    __shared__ float red[4];

    const int t = threadIdx.x;            // owns input cols 2t, 2t+1
    const int ch = blockIdx.x / NPAIR;
    const int pr = blockIdx.x % NPAIR;
    const int r0A = pr * HO;              // strip A: rows r0A..
    const int r0B = (pr + NPAIR) * HO;    // strip B: rows r0B..
    const float* __restrict__ xc = x + (size_t)ch * IH * IW + 2 * t;
    const float* __restrict__ yc = y + (size_t)ch * IH * IW + 2 * t;

    // ---- warmup: both rings + both prefetch pairs (all loads independent) ----
    float2 rxA[KS], ryA[KS], rxB[KS], ryB[KS];
#pragma unroll
    for (int i = 0; i < KS; ++i) {
        rxA[i] = *(const float2*)(xc + min(r0A + i, IH-1) * IW);
        ryA[i] = *(const float2*)(yc + min(r0A + i, IH-1) * IW);
        rxB[i] = *(const float2*)(xc + min(r0B + i, IH-1) * IW);
        ryB[i] = *(const float2*)(yc + min(r0B + i, IH-1) * IW);
    }
    float2 nxA0, nyA0, nxA1, nyA1, nxB0, nyB0, nxB1, nyB1;
    nxA0 = *(const float2*)(xc + min(r0A+11, IH-1)*IW);
    nyA0 = *(const float2*)(yc + min(r0A+11, IH-1)*IW);
    nxA1 = *(const float2*)(xc + min(r0A+12, IH-1)*IW);
    nyA1 = *(const float2*)(yc + min(r0A+12, IH-1)*IW);
    nxB0 = *(const float2*)(xc + min(r0B+11, IH-1)*IW);
    nyB0 = *(const float2*)(yc + min(r0B+11, IH-1)*IW);
    nxB1 = *(const float2*)(xc + min(r0B+12, IH-1)*IW);
    nyB1 = *(const float2*)(yc + min(r0B+12, IH-1)*IW);

    float lsum = 0.f;

    // ---- software-pipelined A/B schedule: every inter-barrier region mixes
    // one strip's vblur (reg FMAs) with the other strip's hblur (LDS reads) ----
    VBLUR(rxA, ryA, nxA0, nyA0, 0);
    SHIFTPREF(rxA, ryA, nxA0, nyA0, nxA1, nyA1, r0A, 0);
    BARRIER();
    for (int k = 0; k < 7; ++k) {
        VBLUR(rxB, ryB, nxB0, nyB0, 1);
        SHIFTPREF(rxB, ryB, nxB0, nyB0, nxB1, nyB1, r0B, k);
        HBLUR(0, r0A, k);
        BARRIER();
        VBLUR(rxA, ryA, nxA0, nyA0, 0);
        SHIFTPREF(rxA, ryA, nxA0, nyA0, nxA1, nyA1, r0A, k + 1);
        HBLUR(1, r0B, k);
        BARRIER();
    }
    VBLUR(rxB, ryB, nxB0, nyB0, 1);
    HBLUR(0, r0A, 7);
    BARRIER();
    HBLUR(1, r0B, 7);

    // ---- block reduce (4 waves of 64) + last-block finalize ----
#pragma unroll
    for (int off = 32; off > 0; off >>= 1) lsum += __shfl_down(lsum, off, 64);
    const int wave = t >> 6, lane = t & 63;
    if (lane == 0) red[wave] = lsum;
    __syncthreads();
    if (t == 0) {
        const float bs = (red[0] + red[1]) + (red[2] + red[3]);
        atomicAdd(acc, (double)bs);
        __threadfence();
        const unsigned int prev = atomicAdd(cnt, 1u);
        if (prev == (unsigned int)(NBLK - 1)) {
            const double total = atomicAdd(acc, 0.0);  // coherent read
            out[0] = (float)(1.0 - total / 12096192.0);  // 48*502*502
        }
    }
}

extern "C" void kernel_launch(void* const* d_in, const int* in_sizes, int n_in,
                              void* d_out, int out_size, void* d_ws, size_t ws_size,
                              hipStream_t stream) {
    const float* x = (const float*)d_in[0];
    const float* y = (const float*)d_in[1];
    float* out = (float*)d_out;
    double* acc = (double*)d_ws;
    unsigned int* cnt = (unsigned int*)((char*)d_ws + 8);

    hipMemsetAsync(d_ws, 0, 16, stream);
    ssim_main<<<NBLK, NT, 0, stream>>>(x, y, acc, cnt, out);
}

// Round 12
// 88.075 us; speedup vs baseline: 1.0352x; 1.0352x over previous
//
#include <hip/hip_runtime.h>

#define IH 512
#define IW 512
#define OH 502
#define OW 502
#define KS 11
#define HO 16                 /* output rows per strip */
#define NSTRIP 32             /* 32 strips of 16 rows */
#define NCH 48                /* 16*3 */
#define NBLK (NCH * NSTRIP)   /* 1536 = 6 blocks/CU */
#define NT 256                /* 256 threads * 2 cols = 512 cols */
#define LROW 528              /* padded LDS row (max read idx 523) */
#define C1f 0.0001f
#define C2f 0.0009f

// Gaussian(sigma=1.5, k=11) weights, precomputed in double precision.
__device__ __constant__ float g_w[KS] = {
    0.00102838f, 0.00759876f, 0.03600077f, 0.10936069f, 0.21300554f,
    0.26601173f, 0.21300554f, 0.10936069f, 0.03600077f, 0.00759876f,
    0.00102838f};

// Raw barrier: drain LDS ops (cross-wave visibility) but leave global
// prefetch loads in flight across the barrier (no vmcnt drain).
#define BARRIER() do {                                        \
    asm volatile("s_waitcnt lgkmcnt(0)" ::: "memory");        \
    __builtin_amdgcn_s_barrier();                             \
} while (0)

__global__ __launch_bounds__(NT, 2) void ssim_main(const float* __restrict__ x,
                                                   const float* __restrict__ y,
                                                   double* __restrict__ acc,
                                                   unsigned int* __restrict__ cnt,
                                                   float* __restrict__ out) {
    __shared__ float lds[5][2][LROW];   /* 5 quantities x 2 rows */
    __shared__ float red[4];

    const int t = threadIdx.x;            // owns input cols 2t, 2t+1
    const int bid = blockIdx.x;
    const int ch = bid / NSTRIP;
    const int strip = bid % NSTRIP;
    const int r0 = strip * HO;
    const float* __restrict__ xc = x + (size_t)ch * IH * IW + 2 * t;
    const float* __restrict__ yc = y + (size_t)ch * IH * IW + 2 * t;

    // ---- anti-convoy stagger: co-resident blocks (CU = bid%256 roughly)
    // get phase offsets 0/500/1000/1500 cyc via a dependent-FMA delay chain,
    // so the 6 blocks/CU run vblur/hblur phases out of lockstep. ----
    {
        const int phase = (bid >> 8) & 3;
        float d = (float)t + 1.0f;
        for (int i = 0; i < phase * 64; ++i)       // wave-uniform trip count
            d = fmaf(d, 1.0000001f, 0.0000001f);   // serial chain, ~8 cyc/iter
        asm volatile("" :: "v"(d));                // sink: not eliminable
    }

    // ---- warmup: ring holds input rows r0 .. r0+10 (static indices) ----
    float2 rx[KS], ry[KS];
#pragma unroll
    for (int i = 0; i < KS; ++i) {
        const int gr = min(r0 + i, IH - 1);
        rx[i] = *(const float2*)(xc + gr * IW);
        ry[i] = *(const float2*)(yc + gr * IW);
    }
    float2 nx0, ny0, nx1, ny1;
    {
        const int g0 = min(r0 + 11, IH - 1);
        const int g1 = min(r0 + 12, IH - 1);
        nx0 = *(const float2*)(xc + g0 * IW);
        ny0 = *(const float2*)(yc + g0 * IW);
        nx1 = *(const float2*)(xc + g1 * IW);
        ny1 = *(const float2*)(yc + g1 * IW);
    }

    float lsum = 0.f;

    for (int k = 0; k < HO / 2; ++k) {
        // ---- vblur row A (2k): taps ring[0..10] ----
        {
            float s0[2] = {0.f, 0.f}, s1[2] = {0.f, 0.f}, s2[2] = {0.f, 0.f};
            float s3[2] = {0.f, 0.f}, s4[2] = {0.f, 0.f};
#pragma unroll
            for (int tp = 0; tp < KS; ++tp) {
                const float w = g_w[tp];
                const float2 xv = rx[tp];
                const float2 yv = ry[tp];
                const float wx0 = w * xv.x, wx1 = w * xv.y;
                const float wy0 = w * yv.x, wy1 = w * yv.y;
                s0[0] += wx0;  s0[1] += wx1;
                s1[0] += wy0;  s1[1] += wy1;
                s2[0] = fmaf(wx0, xv.x, s2[0]);  s2[1] = fmaf(wx1, xv.y, s2[1]);
                s3[0] = fmaf(wy0, yv.x, s3[0]);  s3[1] = fmaf(wy1, yv.y, s3[1]);
                s4[0] = fmaf(wx0, yv.x, s4[0]);  s4[1] = fmaf(wx1, yv.y, s4[1]);
            }
            *(float2*)&lds[0][0][2 * t] = make_float2(s0[0], s0[1]);
            *(float2*)&lds[1][0][2 * t] = make_float2(s1[0], s1[1]);
            *(float2*)&lds[2][0][2 * t] = make_float2(s2[0], s2[1]);
            *(float2*)&lds[3][0][2 * t] = make_float2(s3[0], s3[1]);
            *(float2*)&lds[4][0][2 * t] = make_float2(s4[0], s4[1]);
        }
        // ---- vblur row B (2k+1): taps ring[1..10] + nx0/ny0 as tap 10 ----
        {
            float s0[2] = {0.f, 0.f}, s1[2] = {0.f, 0.f}, s2[2] = {0.f, 0.f};
            float s3[2] = {0.f, 0.f}, s4[2] = {0.f, 0.f};
#pragma unroll
            for (int tp = 0; tp < KS; ++tp) {
                const float w = g_w[tp];
                const float2 xv = (tp < KS - 1) ? rx[tp + 1] : nx0;  // static
                const float2 yv = (tp < KS - 1) ? ry[tp + 1] : ny0;
                const float wx0 = w * xv.x, wx1 = w * xv.y;
                const float wy0 = w * yv.x, wy1 = w * yv.y;
                s0[0] += wx0;  s0[1] += wx1;
                s1[0] += wy0;  s1[1] += wy1;
                s2[0] = fmaf(wx0, xv.x, s2[0]);  s2[1] = fmaf(wx1, xv.y, s2[1]);
                s3[0] = fmaf(wy0, yv.x, s3[0]);  s3[1] = fmaf(wy1, yv.y, s3[1]);
                s4[0] = fmaf(wx0, yv.x, s4[0]);  s4[1] = fmaf(wx1, yv.y, s4[1]);
            }
            *(float2*)&lds[0][1][2 * t] = make_float2(s0[0], s0[1]);
            *(float2*)&lds[1][1][2 * t] = make_float2(s1[0], s1[1]);
            *(float2*)&lds[2][1][2 * t] = make_float2(s2[0], s2[1]);
            *(float2*)&lds[3][1][2 * t] = make_float2(s3[0], s3[1]);
            *(float2*)&lds[4][1][2 * t] = make_float2(s4[0], s4[1]);
        }
        BARRIER();   // barrier1: LDS writes visible; prefetch stays in flight

        // ---- shift ring by 2, commit prefetch, issue next prefetch NOW so it
        // flies under hblur + barrier2 + next vblur-A (~1000+ cycles) ----
#pragma unroll
        for (int i = 0; i < KS - 2; ++i) { rx[i] = rx[i + 2]; ry[i] = ry[i + 2]; }
        rx[KS - 2] = nx0; ry[KS - 2] = ny0;
        rx[KS - 1] = nx1; ry[KS - 1] = ny1;
        {
            const int g0 = min(r0 + 2 * k + 13, IH - 1);
            const int g1 = min(r0 + 2 * k + 14, IH - 1);
            nx0 = *(const float2*)(xc + g0 * IW);
            ny0 = *(const float2*)(yc + g0 * IW);
            nx1 = *(const float2*)(xc + g1 * IW);
            ny1 = *(const float2*)(yc + g1 * IW);
        }

        // ---- hblur + ssim: 256 tasks = 2 rows x 128 4-col chunks ----
        {
            const int rr = t >> 7;            // wave-uniform
            const int c4 = (t & 127) * 4;
            const int orow = r0 + 2 * k + rr;
            float m[5][4];
#pragma unroll
            for (int q = 0; q < 5; ++q) {
                float f[16];
#pragma unroll
                for (int a = 0; a < 4; ++a)
                    *(float4*)&f[4 * a] = *(const float4*)&lds[q][rr][c4 + 4 * a];
#pragma unroll
                for (int cc = 0; cc < 4; ++cc) {
                    float s = 0.f;
#pragma unroll
                    for (int tp = 0; tp < KS; ++tp) s = fmaf(g_w[tp], f[cc + tp], s);
                    m[q][cc] = s;
                }
            }
            if (orow < OH) {
#pragma unroll
                for (int cc = 0; cc < 4; ++cc) {
                    const int gc = c4 + cc;
                    if (gc < OW) {
                        const float mux2 = m[0][cc] * m[0][cc];
                        const float muy2 = m[1][cc] * m[1][cc];
                        const float muxy = m[0][cc] * m[1][cc];
                        const float vx = m[2][cc] - mux2;
                        const float vy = m[3][cc] - muy2;
                        const float cxy = m[4][cc] - muxy;
                        const float num = (2.f * muxy + C1f) * (2.f * cxy + C2f);
                        const float den = (mux2 + muy2 + C1f) * (vx + vy + C2f);
                        float r = __builtin_amdgcn_rcpf(den);
                        r = r * fmaf(-den, r, 2.0f);   // Newton step
                        lsum = fmaf(num, r, lsum);
                    }
                }
            }
        }
        BARRIER();   // barrier2: hblur reads done before next iter's writes (WAR)
    }

    // ---- block reduce (4 waves of 64) + last-block finalize ----
#pragma unroll
    for (int off = 32; off > 0; off >>= 1) lsum += __shfl_down(lsum, off, 64);
    const int wave = t >> 6, lane = t & 63;
    if (lane == 0) red[wave] = lsum;
    __syncthreads();
    if (t == 0) {
        const float bs = (red[0] + red[1]) + (red[2] + red[3]);
        atomicAdd(acc, (double)bs);
        __threadfence();
        const unsigned int prev = atomicAdd(cnt, 1u);
        if (prev == (unsigned int)(NBLK - 1)) {
            const double total = atomicAdd(acc, 0.0);  // coherent read
            out[0] = (float)(1.0 - total / 12096192.0);  // 48*502*502
        }
    }
}

extern "C" void kernel_launch(void* const* d_in, const int* in_sizes, int n_in,
                              void* d_out, int out_size, void* d_ws, size_t ws_size,
                              hipStream_t stream) {
    const float* x = (const float*)d_in[0];
    const float* y = (const float*)d_in[1];
    float* out = (float*)d_out;
    double* acc = (double*)d_ws;
    unsigned int* cnt = (unsigned int*)((char*)d_ws + 8);

    hipMemsetAsync(d_ws, 0, 16, stream);
    ssim_main<<<NBLK, NT, 0, stream>>>(x, y, acc, cnt, out);
}